// Round 2
// baseline (586.343 us; speedup 1.0000x reference)
//
#include <hip/hip_runtime.h>

typedef __bf16 bf16x8 __attribute__((ext_vector_type(8)));
typedef float f32x4 __attribute__((ext_vector_type(4)));

// ---------- helpers ----------
__device__ __forceinline__ unsigned short f2bf(float f) {
    unsigned u = __builtin_bit_cast(unsigned, f);
    u += 0x7FFFu + ((u >> 16) & 1u);           // RNE
    return (unsigned short)(u >> 16);
}

__device__ __forceinline__ void gload16(void* lds, const void* g) {
    __builtin_amdgcn_global_load_lds((const __attribute__((address_space(1))) void*)g,
                                     (__attribute__((address_space(3))) void*)lds,
                                     16, 0, 0);
}

// ---------- kernel 1: fp32 -> bf16 elementwise ----------
__global__ void k_cvt(const float* __restrict__ in, unsigned short* __restrict__ out, int n8) {
    int i = blockIdx.x * blockDim.x + threadIdx.x;
    if (i >= n8) return;
    float4 a = ((const float4*)in)[i * 2];
    float4 b = ((const float4*)in)[i * 2 + 1];
    ushort4 r0 = { f2bf(a.x), f2bf(a.y), f2bf(a.z), f2bf(a.w) };
    ushort4 r1 = { f2bf(b.x), f2bf(b.y), f2bf(b.z), f2bf(b.w) };
    ((ushort4*)out)[i * 2]     = r0;
    ((ushort4*)out)[i * 2 + 1] = r1;
}

// ---------- kernel 2: fp32 [K][N] -> bf16 [N][K] (transpose + convert) ----------
__global__ void k_transpose(const float* __restrict__ in, unsigned short* __restrict__ out,
                            int K, int N) {
    __shared__ float tile[32][33];
    int n0 = blockIdx.x * 32, k0 = blockIdx.y * 32;
    int tx = threadIdx.x, ty = threadIdx.y;   // (32, 8)
#pragma unroll
    for (int i = 0; i < 32; i += 8)
        tile[ty + i][tx] = in[(size_t)(k0 + ty + i) * N + n0 + tx];
    __syncthreads();
#pragma unroll
    for (int i = 0; i < 32; i += 8)
        out[(size_t)(n0 + ty + i) * K + k0 + tx] = f2bf(tile[tx][ty + i]);
}

// ---------- kernel 3/5: 256-row-tile 4-phase pipelined bf16 GEMM ----------
// A [2048][4096] bf16, Bt [N][4096] bf16 (pre-transposed). BM=256, BK=64.
// MODE 0 (BN=256): QKV projection, RoPE epilogue -> qkvo (q,k) + vto (v^T)
// MODE 1 (BN=128): output projection, fp32 epilogue -> fout
#define MFMA_HALF(MH)                                                                   \
    _Pragma("unroll") for (int ii = 0; ii < 4; ++ii)                                    \
        _Pragma("unroll") for (int j = 0; j < NREP; ++j)                                \
            acc[(MH) * 4 + ii][j] = __builtin_amdgcn_mfma_f32_16x16x32_bf16(            \
                a[ii], b[j], acc[(MH) * 4 + ii][j], 0, 0, 0);

template <int BN, int MODE>
__global__ __launch_bounds__(512, 2) void k_gemm8(
    const unsigned short* __restrict__ A,
    const unsigned short* __restrict__ Bt,
    int GX,
    unsigned short* __restrict__ qkvo,
    unsigned short* __restrict__ vto,
    const float* __restrict__ cosT,
    const float* __restrict__ sinT,
    float* __restrict__ fout)
{
    constexpr int K = 4096, NT = 64;          // 64 K-tiles of BK=64
    constexpr int NREP = BN / 64;             // per-wave N fragments (4 or 2)
    constexpr int AL = 4, BL = BN / 64;       // stage loads per thread
    __shared__ unsigned short As[2][256 * 64];
    __shared__ unsigned short Bs[2][BN * 64];

    const int tid = threadIdx.x;
    const int wid = tid >> 6, lane = tid & 63;
    const int lr = lane & 15, lg = lane >> 4;
    const int wr = wid >> 2, wc = wid & 3;    // 2 (M) x 4 (N) waves

    // XCD-aware swizzle (grid % 8 == 0 in both instantiations)
    const int nwg = gridDim.x;
    const int id = blockIdx.x;
    const int swzid = (id & 7) * (nwg >> 3) + (id >> 3);
    const int bx = swzid % GX, by = swzid / GX;
    const int m0 = by * 256, n0 = bx * BN;

    f32x4 acc[8][NREP] = {};

    // LDS layout: [row][64] bf16 (128B rows), 16B chunk c swizzled c ^= (row&7).
    // Staging writes linearly; the XOR is applied to the GLOBAL source chunk.
    auto stageA = [&](int ts, int bsel) {
#pragma unroll
        for (int l = 0; l < AL; ++l) {
            int c = l * 512 + tid;
            int row = c >> 3, ch = c & 7;
            gload16(&As[bsel][c * 8],
                    A + (size_t)(m0 + row) * K + ts * 64 + ((ch ^ (row & 7)) * 8));
        }
    };
    auto stageB = [&](int ts, int bsel) {
#pragma unroll
        for (int l = 0; l < BL; ++l) {
            int c = l * 512 + tid;
            int row = c >> 3, ch = c & 7;
            gload16(&Bs[bsel][c * 8],
                    Bt + (size_t)(n0 + row) * K + ts * 64 + ((ch ^ (row & 7)) * 8));
        }
    };
    auto readA = [&](int bsel, int mh, int kh, bf16x8* a) {
#pragma unroll
        for (int ii = 0; ii < 4; ++ii) {
            int row = wr * 128 + (mh * 4 + ii) * 16 + lr;
            a[ii] = *(const bf16x8*)&As[bsel][row * 64 + ((((kh << 2) | lg) ^ (row & 7)) * 8)];
        }
    };
    auto readB = [&](int bsel, int kh, bf16x8* b) {
#pragma unroll
        for (int j = 0; j < NREP; ++j) {
            int row = wc * (BN / 4) + j * 16 + lr;
            b[j] = *(const bf16x8*)&Bs[bsel][row * 64 + ((((kh << 2) | lg) ^ (row & 7)) * 8)];
        }
    };

    // 4-phase K-tile: P1=(mh0,kh0)+stageA(t+1), P2=(mh1,kh0),
    //                 P3=(mh0,kh1),             P4=(mh1,kh1)+stageB(t+2)+vmcnt(BL)
    auto ktile = [&](int t, int cb) {
        bf16x8 a[4], b[NREP];
        // P1
        readA(cb, 0, 0, a); readB(cb, 0, b);
        stageA((t + 1) & (NT - 1), cb ^ 1);
        __builtin_amdgcn_s_barrier();
        asm volatile("s_waitcnt lgkmcnt(0)" ::: "memory");
        __builtin_amdgcn_s_setprio(1);
        MFMA_HALF(0)
        __builtin_amdgcn_s_setprio(0);
        __builtin_amdgcn_s_barrier();
        // P2 (B kh0 frags persist in regs)
        readA(cb, 1, 0, a);
        __builtin_amdgcn_s_barrier();
        asm volatile("s_waitcnt lgkmcnt(0)" ::: "memory");
        __builtin_amdgcn_s_setprio(1);
        MFMA_HALF(1)
        __builtin_amdgcn_s_setprio(0);
        __builtin_amdgcn_s_barrier();
        // P3
        readA(cb, 0, 1, a); readB(cb, 1, b);
        __builtin_amdgcn_s_barrier();
        asm volatile("s_waitcnt lgkmcnt(0)" ::: "memory");
        __builtin_amdgcn_s_setprio(1);
        MFMA_HALF(0)
        __builtin_amdgcn_s_setprio(0);
        __builtin_amdgcn_s_barrier();
        // P4
        readA(cb, 1, 1, a);
        stageB((t + 2) & (NT - 1), cb);
        __builtin_amdgcn_s_barrier();
        asm volatile("s_waitcnt lgkmcnt(0)" ::: "memory");
        __builtin_amdgcn_s_setprio(1);
        MFMA_HALF(1)
        __builtin_amdgcn_s_setprio(0);
        asm volatile("s_waitcnt vmcnt(%0)" :: "n"(BL) : "memory");
        __builtin_amdgcn_s_barrier();
    };

    // prologue: A(0),B(0) landed; B(1) in flight
    stageA(0, 0); stageB(0, 0); stageB(1, 1);
    asm volatile("s_waitcnt vmcnt(%0)" :: "n"(BL) : "memory");
    __builtin_amdgcn_s_barrier();

    for (int tt = 0; tt < NT / 2; ++tt) { ktile(2 * tt, 0); ktile(2 * tt + 1, 1); }
    asm volatile("s_waitcnt vmcnt(0)" ::: "memory");   // drain tail stages before exit

    if constexpr (MODE == 0) {
        // columns: [0,4096) q | [4096,5120) k | [5120,6144) v (5120 % 256 == 0, no mixed blocks)
#pragma unroll
        for (int j = 0; j < NREP; ++j) {
            const int ng = n0 + wc * (BN / 4) + j * 16 + lr;
            const int d = ng & 127;
            const bool isv = (ng >= 5120);
#pragma unroll
            for (int i = 0; i < 8; ++i) {
#pragma unroll
                for (int r = 0; r < 4; ++r) {
                    const int sg = m0 + wr * 128 + i * 16 + lg * 4 + r;
                    float v = acc[i][j][r];
                    float part = __shfl_xor(v, 1, 64);   // paired rope element (col^1)
                    if (!isv) {
                        float cc = cosT[sg * 64 + (d >> 1)];
                        float ss = sinT[sg * 64 + (d >> 1)];
                        v = (d & 1) ? fmaf(part, ss, v * cc) : fmaf(-part, ss, v * cc);
                        qkvo[(size_t)sg * 6144 + ng] = f2bf(v);
                    } else {
                        vto[(size_t)(ng - 5120) * 2048 + sg] = f2bf(v);
                    }
                }
            }
        }
    } else {
#pragma unroll
        for (int j = 0; j < NREP; ++j) {
            const int ng = n0 + wc * (BN / 4) + j * 16 + lr;
#pragma unroll
            for (int i = 0; i < 8; ++i) {
#pragma unroll
                for (int r = 0; r < 4; ++r) {
                    const int sg = m0 + wr * 128 + i * 16 + lg * 4 + r;
                    fout[(size_t)sg * 4096 + ng] = acc[i][j][r];
                }
            }
        }
    }
}

// ---------- kernel 4: causal GQA flash attention ----------
// qkv: [2048][6144] bf16 (q roped | k roped | unused v cols)
// vt:  [1024][2048] bf16 (v transposed: [kv_head*128+d][s])
// ao:  [2048][4096] bf16 attention output
__global__ __launch_bounds__(256) void k_attn(
    const unsigned short* __restrict__ qkv,
    const unsigned short* __restrict__ vt,
    unsigned short* __restrict__ ao)
{
    __shared__ unsigned short Ks[32 * 128];   // [kp][d], chunks xor-swizzled by (kp&7)
    __shared__ unsigned short Vs[128 * 32];   // [d][kp], chunks xor-swizzled by (d&3)
    __shared__ unsigned short Ps[4 * 16 * 32];

    int tid = threadIdx.x, w = tid >> 6, lane = tid & 63;
    int lr = lane & 15, lg = lane >> 4;
    int h = blockIdx.x & 31;
    int qt = 31 - (blockIdx.x >> 5);          // heavy q-tiles first
    int q0 = qt * 64, kvh = h >> 2;

    // Q fragments in registers (wave w owns rows q0+w*16 .. +15)
    int qrow = q0 + w * 16 + lr;
    const unsigned short* qp = qkv + (size_t)qrow * 6144 + h * 128 + lg * 8;
    bf16x8 aq[4];
#pragma unroll
    for (int kb = 0; kb < 4; kb++) aq[kb] = *(const bf16x8*)(qp + kb * 32);

    f32x4 o[8] = {};
    float m[4], l[4];
#pragma unroll
    for (int r = 0; r < 4; r++) { m[r] = -1e30f; l[r] = 0.f; }
    constexpr float SCL2 = 0.08838834764831845f * 1.44269504088896340f; // 1/sqrt(128)*log2(e)

    int c1 = w * 64 + lane;
    int kp1 = c1 >> 4, pc1 = c1 & 15;
    const unsigned short* kgp = qkv + (size_t)kp1 * 6144 + 4096 + kvh * 128 + (pc1 ^ (kp1 & 7)) * 8;
    int d1 = c1 >> 2, pcv = c1 & 3;
    const unsigned short* vgp = vt + (size_t)(kvh * 128 + d1) * 2048 + (pcv ^ (d1 & 3)) * 8;
    unsigned short* Kd1 = &Ks[(w * 64) * 8];
    unsigned short* Kd2 = &Ks[(256 + w * 64) * 8];
    unsigned short* Vd1 = &Vs[(w * 64) * 8];
    unsigned short* Vd2 = &Vs[(256 + w * 64) * 8];

    int nt = 2 * (qt + 1);
    for (int t = 0; t < nt; ++t) {
        int kp0 = t * 32;
        gload16(Kd1, kgp + (size_t)kp0 * 6144);
        gload16(Kd2, kgp + (size_t)kp0 * 6144 + (size_t)16 * 6144);
        gload16(Vd1, vgp + kp0);
        gload16(Vd2, vgp + kp0 + 64 * 2048);
        __syncthreads();

        if (kp0 <= q0 + w * 16 + 15) {      // wave has unmasked work
            f32x4 sc[2] = {};
#pragma unroll
            for (int cb = 0; cb < 2; ++cb) {
                int kp = cb * 16 + lr;
#pragma unroll
                for (int kb = 0; kb < 4; ++kb) {
                    int dcl = kb * 4 + lg;
                    bf16x8 bk = *(const bf16x8*)&Ks[kp * 128 + ((dcl ^ (kp & 7)) * 8)];
                    sc[cb] = __builtin_amdgcn_mfma_f32_16x16x32_bf16(aq[kb], bk, sc[cb], 0, 0, 0);
                }
            }
            if (kp0 + 31 > q0 + w * 16) {   // diagonal tile: causal mask
#pragma unroll
                for (int cb = 0; cb < 2; ++cb) {
                    int kpg = kp0 + cb * 16 + lr;
#pragma unroll
                    for (int r = 0; r < 4; r++) {
                        int qg = q0 + w * 16 + lg * 4 + r;
                        if (kpg > qg) sc[cb][r] = -1e30f;
                    }
                }
            }
            float tm[4];
#pragma unroll
            for (int r = 0; r < 4; r++) tm[r] = fmaxf(sc[0][r], sc[1][r]);
#pragma unroll
            for (int off = 1; off < 16; off <<= 1)
#pragma unroll
                for (int r = 0; r < 4; r++) tm[r] = fmaxf(tm[r], __shfl_xor(tm[r], off, 64));
            float al[4], rs[4];
#pragma unroll
            for (int r = 0; r < 4; r++) {
                float mn = fmaxf(m[r], tm[r]);
                al[r] = exp2f((m[r] - mn) * SCL2);
                m[r] = mn;
                rs[r] = 0.f;
            }
#pragma unroll
            for (int cb = 0; cb < 2; cb++)
#pragma unroll
                for (int r = 0; r < 4; r++) {
                    float p = exp2f((sc[cb][r] - m[r]) * SCL2);
                    sc[cb][r] = p;
                    rs[r] += p;
                }
#pragma unroll
            for (int off = 1; off < 16; off <<= 1)
#pragma unroll
                for (int r = 0; r < 4; r++) rs[r] += __shfl_xor(rs[r], off, 64);
#pragma unroll
            for (int r = 0; r < 4; r++) l[r] = l[r] * al[r] + rs[r];
#pragma unroll
            for (int db = 0; db < 8; db++)
#pragma unroll
                for (int r = 0; r < 4; r++) o[db][r] *= al[r];
#pragma unroll
            for (int cb = 0; cb < 2; cb++)
#pragma unroll
                for (int r = 0; r < 4; r++) {
                    int q = lg * 4 + r, kp = cb * 16 + lr;
                    Ps[w * 512 + q * 32 + (((kp >> 3) ^ (q & 3)) * 8) + (kp & 7)] = f2bf(sc[cb][r]);
                }
            asm volatile("s_waitcnt lgkmcnt(0)" ::: "memory");
            bf16x8 pa = *(const bf16x8*)&Ps[w * 512 + lr * 32 + ((lg ^ (lr & 3)) * 8)];
#pragma unroll
            for (int db = 0; db < 8; db++) {
                int d = db * 16 + lr;
                bf16x8 bv = *(const bf16x8*)&Vs[d * 32 + ((lg ^ (d & 3)) * 8)];
                o[db] = __builtin_amdgcn_mfma_f32_16x16x32_bf16(pa, bv, o[db], 0, 0, 0);
            }
        }
        __syncthreads();
    }

#pragma unroll
    for (int r = 0; r < 4; r++) l[r] = 1.0f / l[r];
#pragma unroll
    for (int db = 0; db < 8; db++)
#pragma unroll
        for (int r = 0; r < 4; r++) {
            int qg = q0 + w * 16 + lg * 4 + r;
            ao[(size_t)qg * 4096 + h * 128 + db * 16 + lr] = f2bf(o[db][r] * l[r]);
        }
}

// ---------- launcher ----------
extern "C" void kernel_launch(void* const* d_in, const int* in_sizes, int n_in,
                              void* d_out, int out_size, void* d_ws, size_t ws_size,
                              hipStream_t stream) {
    const float* hs   = (const float*)d_in[0];
    const float* wq   = (const float*)d_in[1];
    const float* wk   = (const float*)d_in[2];
    const float* wv   = (const float*)d_in[3];
    const float* wo   = (const float*)d_in[4];
    const float* cosT = (const float*)d_in[5];
    const float* sinT = (const float*)d_in[6];
    float* out = (float*)d_out;

    unsigned short* hsb   = (unsigned short*)d_ws;                 // 2048*4096
    unsigned short* wqkvT = hsb   + (size_t)2048 * 4096;           // 6144*4096
    unsigned short* woT   = wqkvT + (size_t)6144 * 4096;           // 4096*4096
    unsigned short* qkvb  = woT   + (size_t)4096 * 4096;           // 2048*6144
    unsigned short* vtb   = qkvb  + (size_t)2048 * 6144;           // 1024*2048
    unsigned short* attnb = vtb   + (size_t)1024 * 2048;           // 2048*4096

    k_cvt<<<4096, 256, 0, stream>>>(hs, hsb, 1048576);
    dim3 tb(32, 8);
    k_transpose<<<dim3(128, 128), tb, 0, stream>>>(wq, wqkvT, 4096, 4096);
    k_transpose<<<dim3(32, 128),  tb, 0, stream>>>(wk, wqkvT + (size_t)4096 * 4096, 4096, 1024);
    k_transpose<<<dim3(32, 128),  tb, 0, stream>>>(wv, wqkvT + (size_t)5120 * 4096, 4096, 1024);
    k_transpose<<<dim3(128, 128), tb, 0, stream>>>(wo, woT, 4096, 4096);

    k_gemm8<256, 0><<<192, 512, 0, stream>>>(hsb, wqkvT, 24, qkvb, vtb, cosT, sinT, nullptr);
    k_attn<<<1024, 256, 0, stream>>>(qkvb, vtb, attnb);
    k_gemm8<128, 1><<<256, 512, 0, stream>>>(attnb, woT, 32, nullptr, nullptr, nullptr, nullptr, out);
}